// Round 18
// baseline (496.132 us; speedup 1.0000x reference)
//
#include <hip/hip_runtime.h>

// FFLayer: out = relu( (x / (||x||_2 + 1e-4)) @ W^T + b )
// x: [131072,1024] f32, W: [256,1024] f32, b: [256] f32, out: [131072,256] f32
//
// Round 18: ZERO-LDS, ZERO-BARRIER K-loop with COMPILER-PROOF register
// pipelining (r4's geometry + m214's asm discipline):
//  - every load is a volatile-asm global_load_dwordx4 (cannot be sunk/DCE'd)
//  - double-buffered named register sets, all indices static post-unroll
//  - steady VM_WAIT(8) (16 loads in flight, retire exactly next step's set)
//  - sched_barrier(0) after each wait (rule #18: block reg-op hoisting)
//  - no barriers -> 16 decorrelated waves/CU hide HBM/L2 latency via TLP
// A per-wave direct-from-HBM in MFMA fragment layout (32B/lane, dense pairs);
// B per-wave direct-from-L2 (Wb bf16, 512KB, L2-resident). ssq exact (f32).
// LDS only for the r4-verified epilogue transpose (67KB -> 2 blocks/CU).

#define IN_F   1024
#define OUT_F  256
#define BATCH  131072
#define BM     64
#define NKS    32      // K-steps of 32 (mfma 16x16x32)
#define EPSV   1e-4f

typedef __attribute__((ext_vector_type(8))) __bf16 bf16x8;
typedef __attribute__((ext_vector_type(4))) __bf16 bf16x4;
typedef __attribute__((ext_vector_type(4))) float  f32x4;

#define VM_WAIT(N) do { asm volatile("s_waitcnt vmcnt(" #N ")" ::: "memory"); \
                        __builtin_amdgcn_sched_barrier(0); } while (0)

#define GLOADF(dst, p) asm volatile("global_load_dwordx4 %0, %1, off" \
                         : "=v"(dst) : "v"(p) : "memory")

// W (f32 [256][1024]) -> bf16 [256][1024] in d_ws (512 KB)
__global__ void wconv_kernel(const float* __restrict__ W, __bf16* __restrict__ Wb) {
  const int t = blockIdx.x * blockDim.x + threadIdx.x;
  const float4 v = reinterpret_cast<const float4*>(W)[t];
  bf16x4 h;
  h[0] = (__bf16)v.x; h[1] = (__bf16)v.y; h[2] = (__bf16)v.z; h[3] = (__bf16)v.w;
  reinterpret_cast<bf16x4*>(Wb)[t] = h;
}

__global__ __launch_bounds__(512, 4)
void ffl_kernel(const float* __restrict__ x, const __bf16* __restrict__ Wb,
                const float* __restrict__ bias, float* __restrict__ out) {
  __shared__ __align__(16) char smem[66816];   // epilogue only

  const int tid  = threadIdx.x;
  const int lane = tid & 63;
  const int wave = tid >> 6;     // 8 waves: 2(M) x 4(N), wave tile 32x64
  const int wr   = wave >> 2;
  const int wc   = wave & 3;
  const int rm   = lane & 15;
  const int q    = lane >> 4;
  const size_t block_row = (size_t)blockIdx.x * BM;

  // A fragment pointers: lane reads rows (wr*32 + m*16 + rm), 8 f32 at q*8
  const float* ap0 = x + (block_row + wr * 32 + rm) * IN_F + q * 8;
  const float* ap1 = ap0 + 16 * IN_F;
  // B fragment pointer: lane reads Wb row (wc*64 + n*16 + rm), 8 bf16 at q*8
  const __bf16* bp0 = Wb + (size_t)(wc * 64 + rm) * IN_F + q * 8;

  f32x4 acc[2][4];
  #pragma unroll
  for (int m = 0; m < 2; ++m)
    #pragma unroll
    for (int n = 0; n < 4; ++n)
      acc[m][n] = (f32x4){0.f, 0.f, 0.f, 0.f};

  // double-buffered pipeline register sets (all statically indexed post-unroll)
  f32x4  Alo[2][2], Ahi[2][2];   // [set][m]  16+16 VGPR
  bf16x8 Bf[2][4];               // [set][n]  32 VGPR

  float ssq0 = 0.f, ssq1 = 0.f;

  auto issue = [&](int s, int k) {   // 8 volatile-asm loads for step k
    const float*  a0 = ap0 + k * 32;
    const float*  a1 = ap1 + k * 32;
    GLOADF(Alo[s][0], a0);
    GLOADF(Ahi[s][0], a0 + 4);
    GLOADF(Alo[s][1], a1);
    GLOADF(Ahi[s][1], a1 + 4);
    #pragma unroll
    for (int n = 0; n < 4; ++n)
      GLOADF(Bf[s][n], bp0 + (size_t)n * 16 * IN_F + k * 32);
  };

  // -------- prologue: sets 0 and 1 in flight, land set 0 --------
  issue(0, 0);
  issue(1, 1);
  VM_WAIT(8);

  // -------- main loop: 32 steps, no barriers --------
  #pragma unroll
  for (int kt = 0; kt < NKS; ++kt) {
    const int p = kt & 1;

    // compute from set p (landed): exact ssq + cvt + 8 MFMA
    bf16x8 aF[2];
    #pragma unroll
    for (int m = 0; m < 2; ++m) {
      const f32x4 lo = Alo[p][m], hi = Ahi[p][m];
      float& ssq = m ? ssq1 : ssq0;
      ssq += lo[0]*lo[0] + lo[1]*lo[1] + lo[2]*lo[2] + lo[3]*lo[3]
           + hi[0]*hi[0] + hi[1]*hi[1] + hi[2]*hi[2] + hi[3]*hi[3];
      bf16x8 a;
      a[0]=(__bf16)lo[0]; a[1]=(__bf16)lo[1]; a[2]=(__bf16)lo[2]; a[3]=(__bf16)lo[3];
      a[4]=(__bf16)hi[0]; a[5]=(__bf16)hi[1]; a[6]=(__bf16)hi[2]; a[7]=(__bf16)hi[3];
      aF[m] = a;
    }
    #pragma unroll
    for (int n = 0; n < 4; ++n) {
      acc[0][n] = __builtin_amdgcn_mfma_f32_16x16x32_bf16(aF[0], Bf[p][n], acc[0][n], 0, 0, 0);
      acc[1][n] = __builtin_amdgcn_mfma_f32_16x16x32_bf16(aF[1], Bf[p][n], acc[1][n], 0, 0, 0);
    }

    // refill set p for step kt+2 (old values fully consumed above)
    if (kt + 2 < NKS) { issue(p, kt + 2); VM_WAIT(8); }
    else if (kt == 30) { VM_WAIT(0); }    // land set for kt=31
  }

  // -------- row L2-norms: reduce lane partials across the 4 q-groups ------
  ssq0 += __shfl_xor(ssq0, 16); ssq0 += __shfl_xor(ssq0, 32);
  ssq1 += __shfl_xor(ssq1, 16); ssq1 += __shfl_xor(ssq1, 32);
  float* norms = reinterpret_cast<float*>(smem + 66560);
  if (q == 0 && wc == 0) {
    norms[wr * 32 + rm]      = 1.0f / (sqrtf(ssq0) + EPSV);
    norms[wr * 32 + 16 + rm] = 1.0f / (sqrtf(ssq1) + EPSV);
  }
  __syncthreads();

  // -------- scale + bias + relu -> LDS transpose (r4-verified) --------
  float* stg = reinterpret_cast<float*>(smem);   // [64][260] f32
  const int col0 = wc * 64 + rm;
  #pragma unroll
  for (int n = 0; n < 4; ++n) {
    const float bn = bias[col0 + n * 16];
    #pragma unroll
    for (int m = 0; m < 2; ++m) {
      #pragma unroll
      for (int j = 0; j < 4; ++j) {
        const int lr = wr * 32 + m * 16 + q * 4 + j;
        stg[lr * 260 + col0 + n * 16] = fmaxf(acc[m][n][j] * norms[lr] + bn, 0.f);
      }
    }
  }
  __syncthreads();

  // -------- coalesced store: 8 rows/wave, full 128B lines --------
  const int r = tid >> 3, p = tid & 7;
  const float* srow = stg + r * 260;
  float* orow = out + (block_row + r) * OUT_F;
  #pragma unroll
  for (int i = 0; i < 8; ++i) {
    const int f = i * 8 + p;
    const f32x4 v = *reinterpret_cast<const f32x4*>(srow + f * 4);
    *reinterpret_cast<f32x4*>(orow + f * 4) = v;
  }
}

extern "C" void kernel_launch(void* const* d_in, const int* in_sizes, int n_in,
                              void* d_out, int out_size, void* d_ws, size_t ws_size,
                              hipStream_t stream) {
  const float* x = (const float*)d_in[0];
  const float* W = (const float*)d_in[1];
  const float* b = (const float*)d_in[2];
  float* out = (float*)d_out;
  __bf16* Wb = (__bf16*)d_ws;   // 512 KB scratch

  wconv_kernel<<<(OUT_F * IN_F / 4) / 256, 256, 0, stream>>>(W, Wb);
  ffl_kernel<<<BATCH / BM, 512, 0, stream>>>(x, Wb, b, out);
}

// Round 19
// 170.366 us; speedup vs baseline: 2.9122x; 2.9122x over previous
//
#include <hip/hip_runtime.h>

// FFLayer: out = relu( (x / (||x||_2 + 1e-4)) @ W^T + b )
// x: [131072,1024] f32, W: [256,1024] f32, b: [256] f32, out: [131072,256] f32
//
// FINAL (= round 12, best measured: 169.85us, absmax 4.9e-4).
// Structure: bf16 MFMA GEMM with normalization folded into the epilogue
// (h = (x@W^T)*inv_norm + b; sum(x^2) computed exactly in f32 during the
// single-conversion phase). All staging via global_load_lds (the only
// HIP-source path that pipelines on gfx950 -- plain/asm reg loads get
// sunk/spilled by the compiler: r2/r3/r4/r18). Triple-buffered A(f32) and
// B(bf16), counted s_waitcnt vmcnt(3) per step (never 0 mid-loop), raw
// s_barrier, per-block K-rotation for DRAM channel spread, XOR-swizzled
// LDS layouts, LDS-transposed coalesced epilogue.
// Measured plateau of this family: ~170us (= 672MB compulsory traffic at
// ~4 TB/s effective; MFMA/VALU/LDS all >=2x headroom; 11 alternative
// hypotheses falsified in rounds 8-18).

#define IN_F   1024
#define OUT_F  256
#define BATCH  131072
#define BM     128
#define NKT    32      // BK=32 compute steps
#define EPSV   1e-4f

typedef __attribute__((ext_vector_type(8))) __bf16 bf16x8;
typedef __attribute__((ext_vector_type(4))) __bf16 bf16x4;
typedef __attribute__((ext_vector_type(4))) float  f32x4;

__device__ __forceinline__ void gload_lds16(const void* g, void* lds) {
  __builtin_amdgcn_global_load_lds(
      (const __attribute__((address_space(1))) void*)g,
      (__attribute__((address_space(3))) void*)lds, 16, 0, 0);
}

#define VM_WAIT(N) do { asm volatile("s_waitcnt vmcnt(" #N ")" ::: "memory"); \
                        __builtin_amdgcn_sched_barrier(0); } while (0)
#define MIDBAR()   do { asm volatile("s_waitcnt lgkmcnt(0)" ::: "memory"); \
                        __builtin_amdgcn_sched_barrier(0); \
                        __builtin_amdgcn_s_barrier(); } while (0)

// W (f32 [256][1024]) -> bf16 [256][1024] in d_ws (512 KB)
__global__ void wconv_kernel(const float* __restrict__ W, __bf16* __restrict__ Wb) {
  const int t = blockIdx.x * blockDim.x + threadIdx.x;
  const float4 v = reinterpret_cast<const float4*>(W)[t];
  bf16x4 h;
  h[0] = (__bf16)v.x; h[1] = (__bf16)v.y; h[2] = (__bf16)v.z; h[3] = (__bf16)v.w;
  reinterpret_cast<bf16x4*>(Wb)[t] = h;
}

__global__ __launch_bounds__(1024, 4)
void ffl_kernel(const float* __restrict__ x, const __bf16* __restrict__ Wb,
                const float* __restrict__ bias, float* __restrict__ out) {
  // LDS map:
  //   Af32  : 3 x 32KB  [0, 98304)          f32 [128][256B], src-swizzled
  //   Abf16 : 8KB       [98304, 106496)     bf16 [128][64B], swizzled
  //   Bb    : 3 x 16KB  [106496, 155648)    bf16 [256][64B], swizzled
  //   part  : 4KB       [155648, 159744)    ssq partials [8][128]
  //   norms : 512B      [159744, 160256)
  //   epilogue stg [128][260] f32 = 133120B reuses [0, 133120)
  __shared__ __align__(16) char smem[160256];
  char* const Ab[3] = {smem, smem + 32768, smem + 65536};
  char* const Abf   = smem + 98304;
  char* const Bb[3] = {smem + 106496, smem + 122880, smem + 139264};

  const int tid  = threadIdx.x;
  const int lane = tid & 63;
  const int wave = tid >> 6;     // 16 waves: 4(M) x 4(N), wave tile 32x64
  const int wr   = wave >> 2;
  const int wc   = wave & 3;
  const int rm   = lane & 15;
  const int q    = lane >> 4;
  const size_t block_row = (size_t)blockIdx.x * BM;
  const int phg = blockIdx.x & 15;            // K-rotation phase (A-groups)

  // ---- A staging: 2 issues/thread/group. Chunk c=2w+i (1KB = 4 rows x 256B).
  const float* aSrc[2]; int aDst[2];
  #pragma unroll
  for (int i = 0; i < 2; ++i) {
    const int c   = 2 * wave + i;
    const int row = 4 * c + (lane >> 4);
    const int s   = (lane & 15) ^ (row & 7);
    aSrc[i] = x + (block_row + row) * IN_F + s * 4;
    aDst[i] = c * 1024;
  }
  // ---- B staging: 1 issue/thread/step. Chunk = wave (1KB = 16 rows x 64B).
  const int brow = 16 * wave + (lane >> 2);
  const int bs   = (lane & 3) ^ ((brow >> 1) & 3);
  const __bf16* bSrc = Wb + (size_t)brow * IN_F + bs * 8;
  const int bDst = wave * 1024;

  // ---- phase-1 coords: wave covers 8 rows x 8 k-slots (bank-uniform)
  const int prow = 8 * wave + ((tid & 63) >> 3);   // 0..127
  const int pgs  = tid & 7;                        // 4-f32 slot within 128B
  const int p1_wr_byte = prow * 64 + (((pgs >> 1) ^ (prow & 3)) * 16) + (pgs & 1) * 8;

  f32x4 acc[2][4];
  #pragma unroll
  for (int m = 0; m < 2; ++m)
    #pragma unroll
    for (int n = 0; n < 4; ++n)
      acc[m][n] = (f32x4){0.f, 0.f, 0.f, 0.f};

  float pssq = 0.f;

  auto stageA = [&](int g) {      // logical group g -> physical (g+phg)&15
    const int pg = (g + phg) & 15;
    gload_lds16(aSrc[0] + pg * 64, Ab[g % 3] + aDst[0]);
    gload_lds16(aSrc[1] + pg * 64, Ab[g % 3] + aDst[1]);
  };
  auto stageB = [&](int kt) {     // logical step -> physical (kt+2*phg)&31
    const int pk = (kt + 2 * phg) & 31;
    gload_lds16(bSrc + pk * 32, Bb[kt % 3] + bDst);
  };

  // -------- prologue: A0(2) B0 A1(2) B1 = 6 issued --------
  stageA(0);
  stageB(0);
  stageA(1);
  stageB(1);
  VM_WAIT(3);                    // retire A0,B0; flight = [A1a A1b B1]
  __builtin_amdgcn_s_barrier();

  // -------- main loop: 32 steps of BK=32 --------
  #pragma unroll
  for (int kt = 0; kt < NKT; ++kt) {
    if (kt + 2 < NKT) stageB(kt + 2);                              // 1 inst
    if ((kt & 1) == 0 && (kt / 2 + 2) < 16) stageA(kt / 2 + 2);    // 2 insts

    // ---- phase 1: f32 tile -> ssq + bf16 tile (each element ONCE) ----
    {
      const char* abuf = Ab[(kt >> 1) % 3];
      const int sg = (kt & 1) * 8 + pgs;
      const f32x4 v = *reinterpret_cast<const f32x4*>(
          abuf + prow * 256 + ((sg ^ (prow & 7)) * 16));
      pssq += v[0]*v[0] + v[1]*v[1] + v[2]*v[2] + v[3]*v[3];
      bf16x4 hb;
      hb[0] = (__bf16)v[0]; hb[1] = (__bf16)v[1];
      hb[2] = (__bf16)v[2]; hb[3] = (__bf16)v[3];
      *reinterpret_cast<bf16x4*>(Abf + p1_wr_byte) = hb;
    }
    MIDBAR();

    // ---- phase 2: bf16 frags -> MFMA ----
    bf16x8 aF[2];
    #pragma unroll
    for (int m = 0; m < 2; ++m) {
      const int ra = wr * 32 + m * 16 + rm;
      aF[m] = *reinterpret_cast<const bf16x8*>(
          Abf + ra * 64 + ((q ^ (ra & 3)) * 16));
    }
    #pragma unroll
    for (int n = 0; n < 4; ++n) {
      const int rb = wc * 64 + n * 16 + rm;
      const bf16x8 bF = *reinterpret_cast<const bf16x8*>(
          Bb[kt % 3] + rb * 64 + ((q ^ ((rb >> 1) & 3)) * 16));
      acc[0][n] = __builtin_amdgcn_mfma_f32_16x16x32_bf16(aF[0], bF, acc[0][n], 0, 0, 0);
      acc[1][n] = __builtin_amdgcn_mfma_f32_16x16x32_bf16(aF[1], bF, acc[1][n], 0, 0, 0);
    }

    // FIFO-simulated waits (retire exactly what step kt+1 needs):
    if (kt <= 27)      { VM_WAIT(3); }
    else if (kt <= 29) { VM_WAIT(1); }
    else               { VM_WAIT(0); }
    __builtin_amdgcn_s_barrier();
  }

  // -------- row L2-norms: partials -> LDS reduce --------
  float* partials = reinterpret_cast<float*>(smem + 155648);
  partials[pgs * 128 + prow] = pssq;
  __syncthreads();
  float* norms = reinterpret_cast<float*>(smem + 159744);
  if (tid < 128) {
    float s = 0.f;
    #pragma unroll
    for (int g = 0; g < 8; ++g) s += partials[g * 128 + tid];
    norms[tid] = 1.0f / (sqrtf(s) + EPSV);
  }
  __syncthreads();

  // -------- scale + bias + relu -> LDS transpose --------
  float* stg = reinterpret_cast<float*>(smem);   // [128][260] f32 = 133120B
  const int col0 = wc * 64 + rm;
  #pragma unroll
  for (int n = 0; n < 4; ++n) {
    const float bn = bias[col0 + n * 16];
    #pragma unroll
    for (int m = 0; m < 2; ++m) {
      #pragma unroll
      for (int j = 0; j < 4; ++j) {
        const int lr = wr * 32 + m * 16 + q * 4 + j;
        stg[lr * 260 + col0 + n * 16] = fmaxf(acc[m][n][j] * norms[lr] + bn, 0.f);
      }
    }
  }
  __syncthreads();

  // -------- coalesced store: full 128B lines --------
  const int r = tid >> 3, p = tid & 7;       // 128 rows, 8 threads/row
  const float* srow = stg + r * 260;
  float* orow = out + (block_row + r) * OUT_F;
  #pragma unroll
  for (int i = 0; i < 8; ++i) {
    const int f = i * 8 + p;
    const f32x4 v = *reinterpret_cast<const f32x4*>(srow + f * 4);
    *reinterpret_cast<f32x4*>(orow + f * 4) = v;
  }
}

extern "C" void kernel_launch(void* const* d_in, const int* in_sizes, int n_in,
                              void* d_out, int out_size, void* d_ws, size_t ws_size,
                              hipStream_t stream) {
  const float* x = (const float*)d_in[0];
  const float* W = (const float*)d_in[1];
  const float* b = (const float*)d_in[2];
  float* out = (float*)d_out;
  __bf16* Wb = (__bf16*)d_ws;   // 512 KB scratch

  wconv_kernel<<<(OUT_F * IN_F / 4) / 256, 256, 0, stream>>>(W, Wb);
  ffl_kernel<<<BATCH / BM, 1024, 0, stream>>>(x, Wb, b, out);
}